// Round 5
// baseline (1372.751 us; speedup 1.0000x reference)
//
#include <hip/hip_runtime.h>
#include <cstdint>
#include <cstddef>

// Problem constants (fixed by the reference)
#define B_ROWS 8192
#define E_EXP  8

// All harness tensors are fp32 (reference dtype). We keep fp32 end-to-end
// except the GEMM operands, which are rounded to bf16 for MFMA.

typedef unsigned short ushort_t;
typedef short bf16x8 __attribute__((ext_vector_type(8)));
typedef float f32x4  __attribute__((ext_vector_type(4)));

__device__ __forceinline__ ushort_t f2b(float f) {
  union { float f; unsigned int i; } v; v.f = f;
  unsigned int u = v.i;
  unsigned int r = (u + 0x7fffu + ((u >> 16) & 1u)) >> 16;
  return (ushort_t)r;
}
__device__ __forceinline__ float eluf(float x) {
  return x > 0.f ? x : (__expf(x) - 1.f);
}

// ---------------------------------------------------------------------------
// Weight transpose + fp32->bf16: w flat [R][C] -> wT [C][R] bf16.
// block (64,16), grid (C/64, R/64). All dims divisible by 64 here.
// ---------------------------------------------------------------------------
__global__ void transpose_k(const float* __restrict__ src,
                            ushort_t* __restrict__ dst, int R, int C) {
  __shared__ ushort_t tile[64][65];
  int c0 = blockIdx.x * 64, r0 = blockIdx.y * 64;
  int x = threadIdx.x, y = threadIdx.y;
#pragma unroll
  for (int i = 0; i < 4; ++i)
    tile[y + 16 * i][x] = f2b(src[(size_t)(r0 + y + 16 * i) * C + c0 + x]);
  __syncthreads();
#pragma unroll
  for (int i = 0; i < 4; ++i)
    dst[(size_t)(c0 + y + 16 * i) * R + r0 + x] = tile[x][y + 16 * i];
}

// ---------------------------------------------------------------------------
// Gating MLP (pure fp32): coeff[b,e] = softmax(elu(elu(x@g0)@g1)@g2)
// 128 threads handle 4 rows; thread t owns hidden unit t.
// ---------------------------------------------------------------------------
__global__ __launch_bounds__(128) void gate_k(
    const float* __restrict__ z, const float* __restrict__ c,
    const float* __restrict__ g0w, const float* __restrict__ g0b,
    const float* __restrict__ g1w, const float* __restrict__ g1b,
    const float* __restrict__ g2w, const float* __restrict__ g2b,
    float* __restrict__ coeff) {
  __shared__ float xs[4][320];
  __shared__ float h1[4][128];
  __shared__ float h2[4][128];
  __shared__ float lg[4][8];
  int t = threadIdx.x;
  int r0 = blockIdx.x * 4;
  for (int idx = t; idx < 4 * 320; idx += 128) {
    int r = idx / 320, j = idx % 320;
    xs[r][j] = (j < 64) ? z[(size_t)(r0 + r) * 64 + j]
                        : c[(size_t)(r0 + r) * 256 + j - 64];
  }
  __syncthreads();
  {
    float bb = g0b[t];
    float a0 = bb, a1 = bb, a2 = bb, a3 = bb;
    for (int j = 0; j < 320; ++j) {
      float wv = g0w[j * 128 + t];
      a0 += xs[0][j] * wv; a1 += xs[1][j] * wv;
      a2 += xs[2][j] * wv; a3 += xs[3][j] * wv;
    }
    h1[0][t] = eluf(a0); h1[1][t] = eluf(a1);
    h1[2][t] = eluf(a2); h1[3][t] = eluf(a3);
  }
  __syncthreads();
  {
    float bb = g1b[t];
    float a0 = bb, a1 = bb, a2 = bb, a3 = bb;
    for (int j = 0; j < 128; ++j) {
      float wv = g1w[j * 128 + t];
      a0 += h1[0][j] * wv; a1 += h1[1][j] * wv;
      a2 += h1[2][j] * wv; a3 += h1[3][j] * wv;
    }
    h2[0][t] = eluf(a0); h2[1][t] = eluf(a1);
    h2[2][t] = eluf(a2); h2[3][t] = eluf(a3);
  }
  __syncthreads();
  if (t < 32) {
    int r = t >> 3, e = t & 7;
    float a = g2b[e];
    for (int j = 0; j < 128; ++j) a += h2[r][j] * g2w[j * 8 + e];
    lg[r][e] = a;
  }
  __syncthreads();
  if (t < 32) {
    int r = t >> 3, e = t & 7;
    float mx = lg[r][0];
#pragma unroll
    for (int i = 1; i < 8; ++i) mx = fmaxf(mx, lg[r][i]);
    float s = 0.f;
#pragma unroll
    for (int i = 0; i < 8; ++i) s += __expf(lg[r][i] - mx);
    coeff[(size_t)(r0 + r) * 8 + e] = __expf(lg[r][e] - mx) / s;
  }
}

// ---------------------------------------------------------------------------
// LayerNorm over concat([z_row, prev_row]) (fp32 in) -> out [B][J] bf16
// one row per 128-thread block
// ---------------------------------------------------------------------------
__global__ __launch_bounds__(128) void ln_concat_k(
    const float* __restrict__ z, const float* __restrict__ prev,
    ushort_t* __restrict__ out, int Pw, int J) {
  int row = blockIdx.x, t = threadIdx.x;
  float vals[9];
  int n = (J + 127) >> 7;
  float s = 0.f, s2 = 0.f;
  for (int k = 0; k < n; ++k) {
    int i = t + (k << 7);
    float x = 0.f;
    if (i < J)
      x = (i < 64) ? z[(size_t)row * 64 + i] : prev[(size_t)row * Pw + i - 64];
    vals[k] = x; s += x; s2 += x * x;
  }
  for (int off = 32; off > 0; off >>= 1) {
    s += __shfl_down(s, off);
    s2 += __shfl_down(s2, off);
  }
  __shared__ float red[4];
  int wid = t >> 6, lane = t & 63;
  if (lane == 0) { red[wid * 2] = s; red[wid * 2 + 1] = s2; }
  __syncthreads();
  float S = red[0] + red[2], S2 = red[1] + red[3];
  float inv = 1.f / (float)J;
  float m = S * inv;
  float var = S2 * inv - m * m;
  float rstd = rsqrtf(var + 1e-5f);
  for (int k = 0; k < n; ++k) {
    int i = t + (k << 7);
    if (i < J) out[(size_t)row * J + i] = f2b((vals[k] - m) * rstd);
  }
}

// ---------------------------------------------------------------------------
// Fused MoE GEMM: out[b,k] = act( sum_e c[b,e]*(inp[b,:]@w[e,:,k]) + (c@bias)[b,k] )
// Flattened reduction Kd = E*J, BK=64 slices never cross experts (J%64==0).
// Expert mixing via Horner accumulator rescale at expert boundaries.
// 128x128 block tile, 4 waves of 64x64, mfma_f32_16x16x32_bf16, fp32 output.
//
// Cache policy (round 5): A (inp) staging uses NT (CPol bit1) — each block's
// A-tile is block-private stream within its XCD, while the W-tile (2.23 MB)
// is shared by all ~64 co-resident blocks of the XCD (ct == blockid%8 == XCD)
// and must stay L2-resident. Round-4 counters showed W thrash: FETCH 567 MB
// vs 36 MB unique.
// LDS: coeff/ratio/bias arrays padded to stride 9 (round-4 showed 2.3M bank-
// conflict cycles from the *8-stride reads: 4-way same-bank).
// ---------------------------------------------------------------------------
__device__ __forceinline__ void gload16(const void* g, void* l) {
  __builtin_amdgcn_global_load_lds(
      (const __attribute__((address_space(1))) void*)g,
      (__attribute__((address_space(3))) void*)l, 16, 0, 0);
}
__device__ __forceinline__ void gload16_nt(const void* g, void* l) {
  __builtin_amdgcn_global_load_lds(
      (const __attribute__((address_space(1))) void*)g,
      (__attribute__((address_space(3))) void*)l, 16, 0, 2 /* NT */);
}

__global__ __launch_bounds__(256, 2) void moe_gemm_k(
    const ushort_t* __restrict__ inp,   // [B][J] bf16 (LN'd concat)
    const ushort_t* __restrict__ wT,    // [K][E*J] bf16 (pre-transposed)
    const float* __restrict__ bias,     // [E][K] fp32 (original)
    const float* __restrict__ coeff,    // [B][8] fp32
    float* __restrict__ out,            // [B][K] fp32
    int J, int K, int do_elu) {
  const int Kd = E_EXP * J;
  const int nj = J >> 6;
  __shared__ short As[16 * 512];      // [s2][rg8][lane64][8 bf16] = 16KB
  __shared__ short Wsm[16 * 512];     // same layout for W            16KB
  __shared__ float coeff_s[128 * 9];  // [row][e] stride 9 (bank-conflict pad)
  __shared__ float ratio_s[128 * 9];  // [row][e]: e<7 -> c_e/c_{e+1}, e==7 -> c_7
  __shared__ float bias_s[128 * 9];   // [col][e]
  const int t = threadIdx.x;
  const int w = t >> 6, l = t & 63;
  const int bt = blockIdx.y, ct = blockIdx.x;

#pragma unroll
  for (int i = 0; i < 4; ++i) {
    int idx = t + (i << 8);  // 0..1023
    int rw = idx >> 3, e = idx & 7;
    coeff_s[rw * 9 + e] = coeff[(size_t)(bt * 128 + rw) * 8 + e];
    bias_s[rw * 9 + e] = bias[(size_t)e * K + ct * 128 + rw];
  }
  __syncthreads();
#pragma unroll
  for (int i = 0; i < 4; ++i) {
    int idx = t + (i << 8);
    int rw = idx >> 3, e = idx & 7;
    float ce = coeff_s[rw * 9 + e];
    ratio_s[rw * 9 + e] =
        (e < 7) ? (ce / fmaxf(coeff_s[rw * 9 + e + 1], 1e-30f)) : ce;
  }

  // staging addresses: 16 A-blocks + 16 W-blocks of 1KB, 4+4 per wave.
  size_t aoff[4], woff[4];
#pragma unroll
  for (int i = 0; i < 4; ++i) {
    int bi = w * 4 + i;
    int sb = bi >> 3, rg = bi & 7;
    aoff[i] = (size_t)(bt * 128 + rg * 16 + (l & 15)) * J + (sb * 32 + (l >> 4) * 8);
    woff[i] = (size_t)(ct * 128 + rg * 16 + (l & 15)) * Kd + (sb * 32 + (l >> 4) * 8);
  }

  f32x4 acc[4][4];
#pragma unroll
  for (int fm = 0; fm < 4; ++fm)
#pragma unroll
    for (int fn = 0; fn < 4; ++fn) acc[fm][fn] = (f32x4){0.f, 0.f, 0.f, 0.f};

  const int amBase = (w & 1) * 4;
  const int wnBase = (w >> 1) * 4;

  for (int e = 0; e < E_EXP; ++e) {
    size_t ac0 = aoff[0], ac1 = aoff[1], ac2 = aoff[2], ac3 = aoff[3];
    for (int jt = 0; jt < nj; ++jt) {
      __syncthreads();  // previous slice's frag reads done before overwrite
      gload16_nt(inp + ac0, As + (w * 4 + 0) * 512);
      gload16_nt(inp + ac1, As + (w * 4 + 1) * 512);
      gload16_nt(inp + ac2, As + (w * 4 + 2) * 512);
      gload16_nt(inp + ac3, As + (w * 4 + 3) * 512);
      gload16(wT + woff[0], Wsm + (w * 4 + 0) * 512);
      gload16(wT + woff[1], Wsm + (w * 4 + 1) * 512);
      gload16(wT + woff[2], Wsm + (w * 4 + 2) * 512);
      gload16(wT + woff[3], Wsm + (w * 4 + 3) * 512);
      ac0 += 64; ac1 += 64; ac2 += 64; ac3 += 64;
      woff[0] += 64; woff[1] += 64; woff[2] += 64; woff[3] += 64;
      __syncthreads();  // drains vmcnt(0): staged data visible
#pragma unroll
      for (int sb = 0; sb < 2; ++sb) {
        bf16x8 af[4], wf[4];
#pragma unroll
        for (int fm = 0; fm < 4; ++fm)
          af[fm] = *(const bf16x8*)(As + (sb * 8 + amBase + fm) * 512 + l * 8);
#pragma unroll
        for (int fn = 0; fn < 4; ++fn)
          wf[fn] = *(const bf16x8*)(Wsm + (sb * 8 + wnBase + fn) * 512 + l * 8);
#pragma unroll
        for (int fm = 0; fm < 4; ++fm)
#pragma unroll
          for (int fn = 0; fn < 4; ++fn)
            acc[fm][fn] = __builtin_amdgcn_mfma_f32_16x16x32_bf16(
                af[fm], wf[fn], acc[fm][fn], 0, 0, 0);
      }
    }
    // Horner boundary rescale: acc *= c_e/c_{e+1} (e<7), final *= c_7
#pragma unroll
    for (int fm = 0; fm < 4; ++fm) {
      int rbase = (w & 1) * 64 + fm * 16 + ((l >> 4) << 2);
#pragma unroll
      for (int rr = 0; rr < 4; ++rr) {
        float rv = ratio_s[(rbase + rr) * 9 + e];
#pragma unroll
        for (int fn = 0; fn < 4; ++fn) acc[fm][fn][rr] *= rv;
      }
    }
  }

  // epilogue: + coeff@bias, optional ELU, store fp32
  const int wm = (w & 1) * 64, wn = (w >> 1) * 64;
#pragma unroll
  for (int fm = 0; fm < 4; ++fm) {
#pragma unroll
    for (int rr = 0; rr < 4; ++rr) {
      int row = wm + fm * 16 + ((l >> 4) << 2) + rr;
      float cr[8];
#pragma unroll
      for (int e = 0; e < 8; ++e) cr[e] = coeff_s[row * 9 + e];
      size_t orow = (size_t)(bt * 128 + row) * K + ct * 128;
#pragma unroll
      for (int fn = 0; fn < 4; ++fn) {
        int col = wn + fn * 16 + (l & 15);
        float v = acc[fm][fn][rr];
#pragma unroll
        for (int e = 0; e < 8; ++e) v += cr[e] * bias_s[col * 9 + e];
        if (do_elu) v = eluf(v);
        out[orow + col] = v;
      }
    }
  }
}

// ---------------------------------------------------------------------------
extern "C" void kernel_launch(void* const* d_in, const int* in_sizes, int n_in,
                              void* d_out, int out_size, void* d_ws, size_t ws_size,
                              hipStream_t stream) {
  const float* z   = (const float*)d_in[0];
  const float* c   = (const float*)d_in[1];
  const float* g0w = (const float*)d_in[2];
  const float* g0b = (const float*)d_in[3];
  const float* g1w = (const float*)d_in[4];
  const float* g1b = (const float*)d_in[5];
  const float* g2w = (const float*)d_in[6];
  const float* g2b = (const float*)d_in[7];
  const float* w0  = (const float*)d_in[8];
  const float* b0  = (const float*)d_in[9];
  const float* w1  = (const float*)d_in[10];
  const float* b1  = (const float*)d_in[11];
  const float* w2  = (const float*)d_in[12];
  const float* b2  = (const float*)d_in[13];
  const float* w3  = (const float*)d_in[14];
  const float* b3  = (const float*)d_in[15];

  char* ws = (char*)d_ws;
  size_t o = 0;
  auto alloc = [&](size_t bytes) {
    void* p = ws + o;
    o += (bytes + 255) & ~(size_t)255;
    return p;
  };
  ushort_t* wT0 = (ushort_t*)alloc((size_t)2560 * 1024 * 2);
  ushort_t* wT1 = (ushort_t*)alloc((size_t)8704 * 1024 * 2);
  ushort_t* wT2 = (ushort_t*)alloc((size_t)8704 * 1024 * 2);
  ushort_t* wT3 = (ushort_t*)alloc((size_t)8704 * 512 * 2);
  float*    cf  = (float*)alloc((size_t)B_ROWS * 8 * 4);
  ushort_t* inp = (ushort_t*)alloc((size_t)B_ROWS * 1088 * 2);
  float*    hb  = (float*)alloc((size_t)B_ROWS * 1024 * 4);

  dim3 tb(64, 16);
  transpose_k<<<dim3(1024 / 64, 2560 / 64), tb, 0, stream>>>(w0, wT0, 2560, 1024);
  transpose_k<<<dim3(1024 / 64, 8704 / 64), tb, 0, stream>>>(w1, wT1, 8704, 1024);
  transpose_k<<<dim3(1024 / 64, 8704 / 64), tb, 0, stream>>>(w2, wT2, 8704, 1024);
  transpose_k<<<dim3(512 / 64, 8704 / 64), tb, 0, stream>>>(w3, wT3, 8704, 512);

  gate_k<<<B_ROWS / 4, 128, 0, stream>>>(z, c, g0w, g0b, g1w, g1b, g2w, g2b, cf);

  // layer 0: J=320, K=1024, elu
  ln_concat_k<<<B_ROWS, 128, 0, stream>>>(z, c, inp, 256, 320);
  moe_gemm_k<<<dim3(8, 64), 256, 0, stream>>>(inp, wT0, b0, cf, hb, 320, 1024, 1);
  // layer 1: J=1088, K=1024, elu
  ln_concat_k<<<B_ROWS, 128, 0, stream>>>(z, hb, inp, 1024, 1088);
  moe_gemm_k<<<dim3(8, 64), 256, 0, stream>>>(inp, wT1, b1, cf, hb, 1088, 1024, 1);
  // layer 2: J=1088, K=1024, elu
  ln_concat_k<<<B_ROWS, 128, 0, stream>>>(z, hb, inp, 1024, 1088);
  moe_gemm_k<<<dim3(8, 64), 256, 0, stream>>>(inp, wT2, b2, cf, hb, 1088, 1024, 1);
  // layer 3: J=1088, K=512, no act -> d_out (fp32)
  ln_concat_k<<<B_ROWS, 128, 0, stream>>>(z, hb, inp, 1024, 1088);
  moe_gemm_k<<<dim3(4, 64), 256, 0, stream>>>(inp, wT3, b3, cf, (float*)d_out,
                                              1088, 512, 0);
}

// Round 6
// 1068.098 us; speedup vs baseline: 1.2852x; 1.2852x over previous
//
#include <hip/hip_runtime.h>
#include <cstdint>
#include <cstddef>

// Problem constants (fixed by the reference)
#define B_ROWS 8192
#define E_EXP  8

// All harness tensors are fp32 (reference dtype). We keep fp32 end-to-end
// except the GEMM operands, which are rounded to bf16 for MFMA.

typedef unsigned short ushort_t;
typedef short bf16x8 __attribute__((ext_vector_type(8)));
typedef float f32x4  __attribute__((ext_vector_type(4)));

__device__ __forceinline__ ushort_t f2b(float f) {
  union { float f; unsigned int i; } v; v.f = f;
  unsigned int u = v.i;
  unsigned int r = (u + 0x7fffu + ((u >> 16) & 1u)) >> 16;
  return (ushort_t)r;
}
__device__ __forceinline__ float eluf(float x) {
  return x > 0.f ? x : (__expf(x) - 1.f);
}

// ---------------------------------------------------------------------------
// Weight transpose + fp32->bf16: w flat [R][C] -> wT [C][R] bf16.
// block (64,16), grid (C/64, R/64). All dims divisible by 64 here.
// ---------------------------------------------------------------------------
__global__ void transpose_k(const float* __restrict__ src,
                            ushort_t* __restrict__ dst, int R, int C) {
  __shared__ ushort_t tile[64][65];
  int c0 = blockIdx.x * 64, r0 = blockIdx.y * 64;
  int x = threadIdx.x, y = threadIdx.y;
#pragma unroll
  for (int i = 0; i < 4; ++i)
    tile[y + 16 * i][x] = f2b(src[(size_t)(r0 + y + 16 * i) * C + c0 + x]);
  __syncthreads();
#pragma unroll
  for (int i = 0; i < 4; ++i)
    dst[(size_t)(c0 + y + 16 * i) * R + r0 + x] = tile[x][y + 16 * i];
}

// ---------------------------------------------------------------------------
// Gating MLP (pure fp32): coeff[b,e] = softmax(elu(elu(x@g0)@g1)@g2)
// 128 threads handle 4 rows; thread t owns hidden unit t.
// ---------------------------------------------------------------------------
__global__ __launch_bounds__(128) void gate_k(
    const float* __restrict__ z, const float* __restrict__ c,
    const float* __restrict__ g0w, const float* __restrict__ g0b,
    const float* __restrict__ g1w, const float* __restrict__ g1b,
    const float* __restrict__ g2w, const float* __restrict__ g2b,
    float* __restrict__ coeff) {
  __shared__ float xs[4][320];
  __shared__ float h1[4][128];
  __shared__ float h2[4][128];
  __shared__ float lg[4][8];
  int t = threadIdx.x;
  int r0 = blockIdx.x * 4;
  for (int idx = t; idx < 4 * 320; idx += 128) {
    int r = idx / 320, j = idx % 320;
    xs[r][j] = (j < 64) ? z[(size_t)(r0 + r) * 64 + j]
                        : c[(size_t)(r0 + r) * 256 + j - 64];
  }
  __syncthreads();
  {
    float bb = g0b[t];
    float a0 = bb, a1 = bb, a2 = bb, a3 = bb;
    for (int j = 0; j < 320; ++j) {
      float wv = g0w[j * 128 + t];
      a0 += xs[0][j] * wv; a1 += xs[1][j] * wv;
      a2 += xs[2][j] * wv; a3 += xs[3][j] * wv;
    }
    h1[0][t] = eluf(a0); h1[1][t] = eluf(a1);
    h1[2][t] = eluf(a2); h1[3][t] = eluf(a3);
  }
  __syncthreads();
  {
    float bb = g1b[t];
    float a0 = bb, a1 = bb, a2 = bb, a3 = bb;
    for (int j = 0; j < 128; ++j) {
      float wv = g1w[j * 128 + t];
      a0 += h1[0][j] * wv; a1 += h1[1][j] * wv;
      a2 += h1[2][j] * wv; a3 += h1[3][j] * wv;
    }
    h2[0][t] = eluf(a0); h2[1][t] = eluf(a1);
    h2[2][t] = eluf(a2); h2[3][t] = eluf(a3);
  }
  __syncthreads();
  if (t < 32) {
    int r = t >> 3, e = t & 7;
    float a = g2b[e];
    for (int j = 0; j < 128; ++j) a += h2[r][j] * g2w[j * 8 + e];
    lg[r][e] = a;
  }
  __syncthreads();
  if (t < 32) {
    int r = t >> 3, e = t & 7;
    float mx = lg[r][0];
#pragma unroll
    for (int i = 1; i < 8; ++i) mx = fmaxf(mx, lg[r][i]);
    float s = 0.f;
#pragma unroll
    for (int i = 0; i < 8; ++i) s += __expf(lg[r][i] - mx);
    coeff[(size_t)(r0 + r) * 8 + e] = __expf(lg[r][e] - mx) / s;
  }
}

// ---------------------------------------------------------------------------
// LayerNorm over concat([z_row, prev_row]) (fp32 in) -> out [B][J] bf16
// one row per 128-thread block
// ---------------------------------------------------------------------------
__global__ __launch_bounds__(128) void ln_concat_k(
    const float* __restrict__ z, const float* __restrict__ prev,
    ushort_t* __restrict__ out, int Pw, int J) {
  int row = blockIdx.x, t = threadIdx.x;
  float vals[9];
  int n = (J + 127) >> 7;
  float s = 0.f, s2 = 0.f;
  for (int k = 0; k < n; ++k) {
    int i = t + (k << 7);
    float x = 0.f;
    if (i < J)
      x = (i < 64) ? z[(size_t)row * 64 + i] : prev[(size_t)row * Pw + i - 64];
    vals[k] = x; s += x; s2 += x * x;
  }
  for (int off = 32; off > 0; off >>= 1) {
    s += __shfl_down(s, off);
    s2 += __shfl_down(s2, off);
  }
  __shared__ float red[4];
  int wid = t >> 6, lane = t & 63;
  if (lane == 0) { red[wid * 2] = s; red[wid * 2 + 1] = s2; }
  __syncthreads();
  float S = red[0] + red[2], S2 = red[1] + red[3];
  float inv = 1.f / (float)J;
  float m = S * inv;
  float var = S2 * inv - m * m;
  float rstd = rsqrtf(var + 1e-5f);
  for (int k = 0; k < n; ++k) {
    int i = t + (k << 7);
    if (i < J) out[(size_t)row * J + i] = f2b((vals[k] - m) * rstd);
  }
}

// ---------------------------------------------------------------------------
// Fused MoE GEMM: out[b,k] = act( sum_e c[b,e]*(inp[b,:]@w[e,:,k]) + (c@bias)[b,k] )
// Flattened reduction Kd = E*J, BK=64 slices never cross experts (J%64==0).
// Expert mixing via Horner accumulator rescale at expert boundaries.
// 128x128 block tile, 4 waves of 64x64, mfma_f32_16x16x32_bf16, fp32 output.
//
// XCD mapping (round 6): grid = (bt fastest, ct) so XCD = bt%8. Each XCD's
// co-resident blocks share 8 A-tiles (2.23 MB — L2-resident across the 8x
// e-loop re-reads) and stream W once, near-lockstep per ct group. Round-4/5
// counters showed the opposite mapping (ct=XCD) churned 17.8 MB of A per XCD
// through L2, thrashing W: FETCH 567 MB vs 36 MB unique.
// NT on A (round 5) REGRESSED — A's 8x reuse needs L2. Reverted.
// LDS: coeff/ratio/bias padded to stride 9 (round 5: conflicts 2.34M -> 82K).
// ---------------------------------------------------------------------------
__device__ __forceinline__ void gload16(const void* g, void* l) {
  __builtin_amdgcn_global_load_lds(
      (const __attribute__((address_space(1))) void*)g,
      (__attribute__((address_space(3))) void*)l, 16, 0, 0);
}

__global__ __launch_bounds__(256, 2) void moe_gemm_k(
    const ushort_t* __restrict__ inp,   // [B][J] bf16 (LN'd concat)
    const ushort_t* __restrict__ wT,    // [K][E*J] bf16 (pre-transposed)
    const float* __restrict__ bias,     // [E][K] fp32 (original)
    const float* __restrict__ coeff,    // [B][8] fp32
    float* __restrict__ out,            // [B][K] fp32
    int J, int K, int do_elu) {
  const int Kd = E_EXP * J;
  const int nj = J >> 6;
  __shared__ short As[16 * 512];      // [s2][rg8][lane64][8 bf16] = 16KB
  __shared__ short Wsm[16 * 512];     // same layout for W            16KB
  __shared__ float coeff_s[128 * 9];  // [row][e] stride 9 (bank-conflict pad)
  __shared__ float ratio_s[128 * 9];  // [row][e]: e<7 -> c_e/c_{e+1}, e==7 -> c_7
  __shared__ float bias_s[128 * 9];   // [col][e]
  const int t = threadIdx.x;
  const int w = t >> 6, l = t & 63;
  const int bt = blockIdx.x, ct = blockIdx.y;  // bt fastest -> XCD = bt%8

#pragma unroll
  for (int i = 0; i < 4; ++i) {
    int idx = t + (i << 8);  // 0..1023
    int rw = idx >> 3, e = idx & 7;
    coeff_s[rw * 9 + e] = coeff[(size_t)(bt * 128 + rw) * 8 + e];
    bias_s[rw * 9 + e] = bias[(size_t)e * K + ct * 128 + rw];
  }
  __syncthreads();
#pragma unroll
  for (int i = 0; i < 4; ++i) {
    int idx = t + (i << 8);
    int rw = idx >> 3, e = idx & 7;
    float ce = coeff_s[rw * 9 + e];
    ratio_s[rw * 9 + e] =
        (e < 7) ? (ce / fmaxf(coeff_s[rw * 9 + e + 1], 1e-30f)) : ce;
  }

  // staging addresses: 16 A-blocks + 16 W-blocks of 1KB, 4+4 per wave.
  size_t aoff[4], woff[4];
#pragma unroll
  for (int i = 0; i < 4; ++i) {
    int bi = w * 4 + i;
    int sb = bi >> 3, rg = bi & 7;
    aoff[i] = (size_t)(bt * 128 + rg * 16 + (l & 15)) * J + (sb * 32 + (l >> 4) * 8);
    woff[i] = (size_t)(ct * 128 + rg * 16 + (l & 15)) * Kd + (sb * 32 + (l >> 4) * 8);
  }

  f32x4 acc[4][4];
#pragma unroll
  for (int fm = 0; fm < 4; ++fm)
#pragma unroll
    for (int fn = 0; fn < 4; ++fn) acc[fm][fn] = (f32x4){0.f, 0.f, 0.f, 0.f};

  const int amBase = (w & 1) * 4;
  const int wnBase = (w >> 1) * 4;

  for (int e = 0; e < E_EXP; ++e) {
    size_t ac0 = aoff[0], ac1 = aoff[1], ac2 = aoff[2], ac3 = aoff[3];
    for (int jt = 0; jt < nj; ++jt) {
      __syncthreads();  // previous slice's frag reads done before overwrite
      gload16(inp + ac0, As + (w * 4 + 0) * 512);
      gload16(inp + ac1, As + (w * 4 + 1) * 512);
      gload16(inp + ac2, As + (w * 4 + 2) * 512);
      gload16(inp + ac3, As + (w * 4 + 3) * 512);
      gload16(wT + woff[0], Wsm + (w * 4 + 0) * 512);
      gload16(wT + woff[1], Wsm + (w * 4 + 1) * 512);
      gload16(wT + woff[2], Wsm + (w * 4 + 2) * 512);
      gload16(wT + woff[3], Wsm + (w * 4 + 3) * 512);
      ac0 += 64; ac1 += 64; ac2 += 64; ac3 += 64;
      woff[0] += 64; woff[1] += 64; woff[2] += 64; woff[3] += 64;
      __syncthreads();  // drains vmcnt(0): staged data visible
#pragma unroll
      for (int sb = 0; sb < 2; ++sb) {
        bf16x8 af[4], wf[4];
#pragma unroll
        for (int fm = 0; fm < 4; ++fm)
          af[fm] = *(const bf16x8*)(As + (sb * 8 + amBase + fm) * 512 + l * 8);
#pragma unroll
        for (int fn = 0; fn < 4; ++fn)
          wf[fn] = *(const bf16x8*)(Wsm + (sb * 8 + wnBase + fn) * 512 + l * 8);
#pragma unroll
        for (int fm = 0; fm < 4; ++fm)
#pragma unroll
          for (int fn = 0; fn < 4; ++fn)
            acc[fm][fn] = __builtin_amdgcn_mfma_f32_16x16x32_bf16(
                af[fm], wf[fn], acc[fm][fn], 0, 0, 0);
      }
    }
    // Horner boundary rescale: acc *= c_e/c_{e+1} (e<7), final *= c_7
#pragma unroll
    for (int fm = 0; fm < 4; ++fm) {
      int rbase = (w & 1) * 64 + fm * 16 + ((l >> 4) << 2);
#pragma unroll
      for (int rr = 0; rr < 4; ++rr) {
        float rv = ratio_s[(rbase + rr) * 9 + e];
#pragma unroll
        for (int fn = 0; fn < 4; ++fn) acc[fm][fn][rr] *= rv;
      }
    }
  }

  // epilogue: + coeff@bias, optional ELU, store fp32
  const int wm = (w & 1) * 64, wn = (w >> 1) * 64;
#pragma unroll
  for (int fm = 0; fm < 4; ++fm) {
#pragma unroll
    for (int rr = 0; rr < 4; ++rr) {
      int row = wm + fm * 16 + ((l >> 4) << 2) + rr;
      float cr[8];
#pragma unroll
      for (int e = 0; e < 8; ++e) cr[e] = coeff_s[row * 9 + e];
      size_t orow = (size_t)(bt * 128 + row) * K + ct * 128;
#pragma unroll
      for (int fn = 0; fn < 4; ++fn) {
        int col = wn + fn * 16 + (l & 15);
        float v = acc[fm][fn][rr];
#pragma unroll
        for (int e = 0; e < 8; ++e) v += cr[e] * bias_s[col * 9 + e];
        if (do_elu) v = eluf(v);
        out[orow + col] = v;
      }
    }
  }
}

// ---------------------------------------------------------------------------
extern "C" void kernel_launch(void* const* d_in, const int* in_sizes, int n_in,
                              void* d_out, int out_size, void* d_ws, size_t ws_size,
                              hipStream_t stream) {
  const float* z   = (const float*)d_in[0];
  const float* c   = (const float*)d_in[1];
  const float* g0w = (const float*)d_in[2];
  const float* g0b = (const float*)d_in[3];
  const float* g1w = (const float*)d_in[4];
  const float* g1b = (const float*)d_in[5];
  const float* g2w = (const float*)d_in[6];
  const float* g2b = (const float*)d_in[7];
  const float* w0  = (const float*)d_in[8];
  const float* b0  = (const float*)d_in[9];
  const float* w1  = (const float*)d_in[10];
  const float* b1  = (const float*)d_in[11];
  const float* w2  = (const float*)d_in[12];
  const float* b2  = (const float*)d_in[13];
  const float* w3  = (const float*)d_in[14];
  const float* b3  = (const float*)d_in[15];

  char* ws = (char*)d_ws;
  size_t o = 0;
  auto alloc = [&](size_t bytes) {
    void* p = ws + o;
    o += (bytes + 255) & ~(size_t)255;
    return p;
  };
  ushort_t* wT0 = (ushort_t*)alloc((size_t)2560 * 1024 * 2);
  ushort_t* wT1 = (ushort_t*)alloc((size_t)8704 * 1024 * 2);
  ushort_t* wT2 = (ushort_t*)alloc((size_t)8704 * 1024 * 2);
  ushort_t* wT3 = (ushort_t*)alloc((size_t)8704 * 512 * 2);
  float*    cf  = (float*)alloc((size_t)B_ROWS * 8 * 4);
  ushort_t* inp = (ushort_t*)alloc((size_t)B_ROWS * 1088 * 2);
  float*    hb  = (float*)alloc((size_t)B_ROWS * 1024 * 4);

  dim3 tb(64, 16);
  transpose_k<<<dim3(1024 / 64, 2560 / 64), tb, 0, stream>>>(w0, wT0, 2560, 1024);
  transpose_k<<<dim3(1024 / 64, 8704 / 64), tb, 0, stream>>>(w1, wT1, 8704, 1024);
  transpose_k<<<dim3(1024 / 64, 8704 / 64), tb, 0, stream>>>(w2, wT2, 8704, 1024);
  transpose_k<<<dim3(512 / 64, 8704 / 64), tb, 0, stream>>>(w3, wT3, 8704, 512);

  gate_k<<<B_ROWS / 4, 128, 0, stream>>>(z, c, g0w, g0b, g1w, g1b, g2w, g2b, cf);

  // layer 0: J=320, K=1024, elu   (grid: bt fastest -> XCD = bt%8)
  ln_concat_k<<<B_ROWS, 128, 0, stream>>>(z, c, inp, 256, 320);
  moe_gemm_k<<<dim3(64, 8), 256, 0, stream>>>(inp, wT0, b0, cf, hb, 320, 1024, 1);
  // layer 1: J=1088, K=1024, elu
  ln_concat_k<<<B_ROWS, 128, 0, stream>>>(z, hb, inp, 1024, 1088);
  moe_gemm_k<<<dim3(64, 8), 256, 0, stream>>>(inp, wT1, b1, cf, hb, 1088, 1024, 1);
  // layer 2: J=1088, K=1024, elu
  ln_concat_k<<<B_ROWS, 128, 0, stream>>>(z, hb, inp, 1024, 1088);
  moe_gemm_k<<<dim3(64, 8), 256, 0, stream>>>(inp, wT2, b2, cf, hb, 1088, 1024, 1);
  // layer 3: J=1088, K=512, no act -> d_out (fp32)
  ln_concat_k<<<B_ROWS, 128, 0, stream>>>(z, hb, inp, 1024, 1088);
  moe_gemm_k<<<dim3(64, 4), 256, 0, stream>>>(inp, wT3, b3, cf, (float*)d_out,
                                              1088, 512, 0);
}